// Round 2
// 535.126 us; speedup vs baseline: 1.1278x; 1.1278x over previous
//
#include <hip/hip_runtime.h>

// EdgeDecoder: out[b,i,j] = dot(z[b,i,:], w[:H]) + dot(z[b,j,:], w[H:]) + bias
// B=8, N=4096, H=256. ALL tensors fp32 per the reference file.
// Factorized: two thin matvecs (staged in d_ws) + broadcast outer add.
// Memory-bound on the 512 MiB fp32 output store (~87 us at 6.3 TB/s).

#define Bc 8
#define Nc 4096
#define Hc 256

// Native ext-vector type: __builtin_nontemporal_store requires a pointer to
// scalar-or-vector-of-scalar, NOT HIP's float4 class (HIP_vector_type).
typedef float f4 __attribute__((ext_vector_type(4)));

// Kernel 1: per-row dual dot products.
// One wave (64 lanes) per row r in [0, B*N): each lane loads 4 floats of z
// and 4 of each w-half, dual dot, 64-lane shuffle reduce, lane 0 writes fp32.
__global__ __launch_bounds__(256) void ed_dots(
    const float* __restrict__ z,
    const float* __restrict__ w,
    const float* __restrict__ bias,
    float* __restrict__ rowc,
    float* __restrict__ colc)
{
    const int wid  = threadIdx.x >> 6;
    const int lane = threadIdx.x & 63;
    const int r = blockIdx.x * 4 + wid;          // row in [0, B*N)

    const f4 zv = *(const f4*)(z + (size_t)r * Hc + lane * 4);
    const f4 av = *(const f4*)(w + lane * 4);        // w[:H] slice
    const f4 bv = *(const f4*)(w + Hc + lane * 4);   // w[H:] slice

    float s1 = zv.x * av.x + zv.y * av.y + zv.z * av.z + zv.w * av.w;
    float s2 = zv.x * bv.x + zv.y * bv.y + zv.z * bv.z + zv.w * bv.w;

    #pragma unroll
    for (int off = 32; off > 0; off >>= 1) {
        s1 += __shfl_down(s1, off, 64);
        s2 += __shfl_down(s2, off, 64);
    }
    if (lane == 0) {
        rowc[r] = s1;
        colc[r] = s2 + bias[0];   // fold bias into the column term
    }
}

// Kernel 2: out[b,i,j] = rowc[b,i] + colc[b,j].
// One block per output row (b,i). COALESCING FIX vs the 603us version:
// thread t writes float4 index (t + c*256) for chunk c=0..3, so each
// global_store_dwordx4 has 64 lanes writing 16 B CONTIGUOUS (1 KB/instr,
// full 64-B lines) instead of a 64-B lane stride (quarter-line writes,
// 4x the transactions). Output is streamed with nontemporal stores; colc
// (16 KB/batch) stays cached and is reused by all 4096 rows of the batch.
__global__ __launch_bounds__(256) void ed_outer(
    const float* __restrict__ rowc,
    const float* __restrict__ colc,
    float* __restrict__ out)
{
    const int bi = blockIdx.x;                 // (b*N + i) in [0, B*N)
    const float r = rowc[bi];
    const int cbase = bi & ~(Nc - 1);          // b*N
    const int t = threadIdx.x;

    const f4* cp = (const f4*)(colc + cbase);
    f4*       o  = (f4*)(out + (size_t)bi * Nc);

    #pragma unroll
    for (int c = 0; c < 4; ++c) {
        f4 v = cp[c * 256 + t];
        v.x += r; v.y += r; v.z += r; v.w += r;
        __builtin_nontemporal_store(v, o + c * 256 + t);
    }
}

extern "C" void kernel_launch(void* const* d_in, const int* in_sizes, int n_in,
                              void* d_out, int out_size, void* d_ws, size_t ws_size,
                              hipStream_t stream) {
    const float* z    = (const float*)d_in[0];   // [B,N,H] fp32
    const float* w    = (const float*)d_in[1];   // [2H] fp32
    const float* bias = (const float*)d_in[2];   // [1] fp32
    float* out = (float*)d_out;                  // [B,N,N] fp32

    float* rowc = (float*)d_ws;           // B*N fp32
    float* colc = rowc + Bc * Nc;         // B*N fp32 (bias folded in)

    ed_dots<<<Bc * Nc / 4, 256, 0, stream>>>(z, w, bias, rowc, colc);
    ed_outer<<<Bc * Nc, 256, 0, stream>>>(rowc, colc, out);
}